// Round 1
// baseline (213.365 us; speedup 1.0000x reference)
//
#include <hip/hip_runtime.h>

// Problem dims (fixed by reference setup_inputs)
#define BS    32
#define NF    64     // n_feat
#define NN    512    // N
#define JJ    4      // J
#define NOUT  128
#define CC    256    // J*NF
#define NC    8      // n-chunks
#define ROWS  64     // NN/NC rows per chunk
#define MJC   2      // m-half chunks per row
#define ROW4  512    // float4 per (b,n) row  (NN*JJ/4; one float4 = one m, j=0..3)
#define CH4   256    // float4 per m-half
#define NPART (NC * MJC)   // 16 partial-y vectors per batch

// Math: y[b,o] = sum_c fc_w[o,c] * T[b,c] + NN*fc_b[o]
//       T[b, j*NF+f] = sum_m S[b,m,j] * X[b,f,m],  S[b,m,j] = sum_n W[b,n,m,j]
// Everything is linear in W, so each (n-chunk, m-half) block computes its own
// partial y directly from its partial S — no global S/P round-trip needed.
//
// Fused kernel: grid = BS*NC*MJC = 512 blocks, 256 threads.
//   Phase A: stream 64 W-rows -> partial S (identical memory pattern to the
//            proven sumW_kernel: coalesced float4, 8-deep unroll, BW-bound).
//   Phase B: Tpart[j][f] = sum_{ml<256} S[j][ml] * X[b][f][mjc*256+ml]
//            (one (j,f) pair per thread; Sl rows padded to 260 floats so the
//             4 per-wave b128 chunks land on 16 distinct banks).
//   Phase C: ypart[o] = sum_c fc_w[o][c] * Tpart[c]  (2 threads per o + shfl).
//            Write 128 floats to workspace (fully overwritten; poison-safe).
__global__ __launch_bounds__(256) void fused_kernel(const float4* __restrict__ W4,
                                                    const float4* __restrict__ X4,
                                                    const float4* __restrict__ fcw4,
                                                    float* __restrict__ Yp) {
    __shared__ __align__(16) float Sl[JJ][260];  // 260: rows start 4 banks apart
    __shared__ __align__(16) float Tl[CC];

    int blk  = blockIdx.x;
    int mjc  = blk & (MJC - 1);
    int rest = blk >> 1;            // MJC == 2
    int nc   = rest & (NC - 1);
    int b    = rest >> 3;           // NC == 8
    int t    = threadIdx.x;
    int m    = mjc * CH4 + t;       // float4 index within row = m index

    // --- Phase A: stream W, partial column-sum over this block's 64 n-rows ---
    {
        const float4* p = W4 + ((size_t)(b * NN + nc * ROWS)) * ROW4 + m;
        float4 acc = make_float4(0.f, 0.f, 0.f, 0.f);
#pragma unroll 8
        for (int r = 0; r < ROWS; ++r) {
            float4 v = p[(size_t)r * ROW4];
            acc.x += v.x; acc.y += v.y; acc.z += v.z; acc.w += v.w;
        }
        // acc.{x,y,z,w} = partial S[m][j=0..3]; consecutive-address writes.
        Sl[0][t] = acc.x; Sl[1][t] = acc.y; Sl[2][t] = acc.z; Sl[3][t] = acc.w;
    }
    __syncthreads();

    // --- Phase B: contract partial S with X over this m-half ---
    {
        int j = t & 3, f = t >> 2;
        const float4* xp = X4 + ((size_t)(b * NF + f)) * (NN / 4) + mjc * (CH4 / 4);
        const float4* sp = (const float4*)(&Sl[j][0]);
        float tp = 0.f;
#pragma unroll
        for (int i = 0; i < CH4 / 4; ++i) {   // 64 float4 = 256 m's
            float4 xv = xp[i];
            float4 sv = sp[i];
            tp += xv.x * sv.x + xv.y * sv.y + xv.z * sv.z + xv.w * sv.w;
        }
        Tl[j * NF + f] = tp;   // channel order c = j*NF + f (matches reshape)
    }
    __syncthreads();

    // --- Phase C: partial y through fc_w; o = t>>1, half = t&1 ---
    {
        int o = t >> 1, h = t & 1;
        const float4* wp  = fcw4 + (size_t)o * (CC / 4) + h * 32;
        const float4* tl4 = (const float4*)Tl;
        float a = 0.f;
#pragma unroll
        for (int u = 0; u < 32; ++u) {
            float4 wv = wp[u];
            float4 tv = tl4[h * 32 + u];
            a += wv.x * tv.x + wv.y * tv.y + wv.z * tv.z + wv.w * tv.w;
        }
        a += __shfl_down(a, 1, 2);
        if (!h) Yp[(size_t)blk * NOUT + o] = a;
    }
}

// Tiny final reduce: out[b,o] = NN*fc_b[o] + sum over the 16 block-partials.
// Reads 256 KB (L2), coalesced over o. ~2-3 us launch-dominated.
__global__ __launch_bounds__(128) void reduce_kernel(const float* __restrict__ Yp,
                                                     const float* __restrict__ fcb,
                                                     float* __restrict__ out) {
    int b = blockIdx.x, o = threadIdx.x;
    float a = (float)NN * fcb[o];
    const float* pp = Yp + (size_t)b * NPART * NOUT + o;
#pragma unroll
    for (int q = 0; q < NPART; ++q) a += pp[q * NOUT];
    out[b * NOUT + o] = a;
}

extern "C" void kernel_launch(void* const* d_in, const int* in_sizes, int n_in,
                              void* d_out, int out_size, void* d_ws, size_t ws_size,
                              hipStream_t stream) {
    // Inputs (setup_inputs order): X, W, fc_w, fc_b, N_batch, mask — all fp32.
    const float4* X4   = (const float4*)d_in[0];
    const float4* W4   = (const float4*)d_in[1];
    const float4* fcw4 = (const float4*)d_in[2];
    const float*  fcb  = (const float*)d_in[3];
    float* out = (float*)d_out;

    // Workspace: 512 partial-y vectors of 128 floats = 256 KB. Fully
    // overwritten by fused_kernel before reduce_kernel reads it (poison-safe).
    float* Yp = (float*)d_ws;

    fused_kernel<<<BS * NC * MJC, 256, 0, stream>>>(W4, X4, fcw4, Yp);
    reduce_kernel<<<BS, 128, 0, stream>>>(Yp, fcb, out);
}